// Round 1
// baseline (429.403 us; speedup 1.0000x reference)
//
#include <hip/hip_runtime.h>
#include <stdint.h>

// ---------------------------------------------------------------------------
// AVFusion: A/V/S projections -> q,k,v -> 2-way softmax attention -> FF(1024)
// Round 0: correctness-first bf16-MFMA pipeline (m97-style 128x128 GEMM tile).
// ---------------------------------------------------------------------------

#define D_MODEL 1024
#define N_HEAD  8
#define DK      128
#define BS      16
#define NSEG    64
#define NSEN    32

typedef __attribute__((ext_vector_type(8))) __bf16 bf16x8;
typedef __attribute__((ext_vector_type(8))) unsigned short u16x8;
typedef __attribute__((ext_vector_type(4))) float f32x4;

__device__ __forceinline__ float bf2f(unsigned short b) {
  union { unsigned int u; float f; } x; x.u = ((unsigned int)b) << 16; return x.f;
}
__device__ __forceinline__ unsigned short f2bf(float f) {
  union { float f; unsigned int u; } x; x.f = f;
  unsigned int u = x.u;
  unsigned int r = (u + 0x7fffu + ((u >> 16) & 1u)) >> 16;  // RNE
  return (unsigned short)r;
}

// fp32 -> bf16 conversion, vectorized by 4
__global__ __launch_bounds__(256)
void f2b_kernel(const float* __restrict__ in, unsigned short* __restrict__ out, int n4) {
  int i = blockIdx.x * 256 + threadIdx.x;
  if (i >= n4) return;
  float4 v = reinterpret_cast<const float4*>(in)[i];
  ushort4 o;
  o.x = f2bf(v.x); o.y = f2bf(v.y); o.z = f2bf(v.z); o.w = f2bf(v.w);
  reinterpret_cast<ushort4*>(out)[i] = o;
}

// async global->LDS, 16B per lane
__device__ __forceinline__ void g2l16(const void* g, void* l) {
  __builtin_amdgcn_global_load_lds(
      (const __attribute__((address_space(1))) void*)g,
      (__attribute__((address_space(3))) void*)l, 16, 0, 0);
}

// C[M,N] = act(A[M,K] @ B[N,K]^T + bias), A/B bf16 row-major, K-contiguous.
// 128x128 block tile, BK=32, 4 waves each owning a 64x64 sub-tile (4x4 frags).
// M % 128 == 0, N % 128 == 0, K % 32 == 0 (all shapes here satisfy this).
template<int RELU, int BF16OUT>
__global__ __launch_bounds__(256)
void gemm_bt(const unsigned short* __restrict__ A, const unsigned short* __restrict__ B,
             const float* __restrict__ bias, void* __restrict__ Cout,
             int M, int N, int K) {
  __shared__ __align__(16) unsigned short lA[128 * 32];
  __shared__ __align__(16) unsigned short lB[128 * 32];

  const int t = threadIdx.x;
  const int m0 = blockIdx.y * 128, n0 = blockIdx.x * 128;
  const int lane = t & 63, wv = t >> 6;
  const int wrow = (wv >> 1) * 64, wcol = (wv & 1) * 64;
  const int fr = lane & 15;        // row/col within fragment
  const int kg = lane >> 4;        // k-group (8 elems each)

  f32x4 acc[4][4] = {};

  const int r  = t >> 2;           // staging row 0..63
  const int c8 = (t & 3) * 8;      // staging k-chunk
  const unsigned short* ga = A + (size_t)(m0 + r) * K + c8;
  const unsigned short* gb = B + (size_t)(n0 + r) * K + c8;

  for (int k0 = 0; k0 < K; k0 += 32) {
    __syncthreads();               // protect LDS from previous iter's readers
    g2l16(ga + k0,          &lA[t * 8]);
    g2l16(ga + k0 + 64 * K, &lA[2048 + t * 8]);
    g2l16(gb + k0,          &lB[t * 8]);
    g2l16(gb + k0 + 64 * K, &lB[2048 + t * 8]);
    __syncthreads();               // drains vmcnt (global_load_lds) too

    u16x8 af[4], bg_[4];
#pragma unroll
    for (int mi = 0; mi < 4; ++mi)
      af[mi] = *reinterpret_cast<const u16x8*>(&lA[(wrow + mi * 16 + fr) * 32 + kg * 8]);
#pragma unroll
    for (int ni = 0; ni < 4; ++ni)
      bg_[ni] = *reinterpret_cast<const u16x8*>(&lB[(wcol + ni * 16 + fr) * 32 + kg * 8]);
#pragma unroll
    for (int mi = 0; mi < 4; ++mi)
#pragma unroll
      for (int ni = 0; ni < 4; ++ni)
        acc[mi][ni] = __builtin_amdgcn_mfma_f32_16x16x32_bf16(
            __builtin_bit_cast(bf16x8, af[mi]), __builtin_bit_cast(bf16x8, bg_[ni]),
            acc[mi][ni], 0, 0, 0);
  }

  // epilogue: C/D layout col = lane&15, row = (lane>>4)*4 + j  [learn_hip m89/m91]
  const int rg = kg * 4;
#pragma unroll
  for (int ni = 0; ni < 4; ++ni) {
    const int gn = n0 + wcol + ni * 16 + fr;
    const float bv = bias ? bias[gn] : 0.0f;
#pragma unroll
    for (int mi = 0; mi < 4; ++mi) {
      const int gm = m0 + wrow + mi * 16 + rg;
#pragma unroll
      for (int j = 0; j < 4; ++j) {
        float v = acc[mi][ni][j] + bv;
        if (RELU) v = v > 0.f ? v : 0.f;
        if (BF16OUT)
          reinterpret_cast<unsigned short*>(Cout)[(size_t)(gm + j) * N + gn] = f2bf(v);
        else
          reinterpret_cast<float*>(Cout)[(size_t)(gm + j) * N + gn] = v;
      }
    }
  }
}

// Attention over the 2-element A/V axis. One block per (b,g); loops s=0..31.
// ctx[b,s,g,h*128+d] = pA*vA[b,g,h*128+d] + (1-pA)*vV[...],
// pA = softmax over {A,V} of (q.k)/sqrt(128).
__global__ __launch_bounds__(256)
void attn_kernel(const unsigned short* __restrict__ q,
                 const unsigned short* __restrict__ kA, const unsigned short* __restrict__ kV,
                 const unsigned short* __restrict__ vA, const unsigned short* __restrict__ vV,
                 unsigned short* __restrict__ ctx) {
  const int bg = blockIdx.x;           // b*64 + g
  const int b = bg >> 6, g = bg & 63;
  __shared__ float sk[4][D_MODEL];     // kA,kV,vA,vV rows (fp32), 16KB
  const size_t row = (size_t)bg * D_MODEL;
  for (int i = threadIdx.x; i < D_MODEL; i += 256) {
    sk[0][i] = bf2f(kA[row + i]);
    sk[1][i] = bf2f(kV[row + i]);
    sk[2][i] = bf2f(vA[row + i]);
    sk[3][i] = bf2f(vV[row + i]);
  }
  __syncthreads();

  const int h = threadIdx.x >> 5;      // 0..7
  const int l = threadIdx.x & 31;      // 0..31 within head group
  const float scale = 0.08838834764831845f;  // 1/sqrt(128)

  for (int s = 0; s < NSEN; ++s) {
    const unsigned short* pq = q + ((size_t)(b * NSEN + s)) * D_MODEL + h * DK;
    float la = 0.f, lv = 0.f;
#pragma unroll
    for (int e = 0; e < 4; ++e) {
      int d = l + e * 32;
      float qv = bf2f(pq[d]);
      la += qv * sk[0][h * DK + d];
      lv += qv * sk[1][h * DK + d];
    }
#pragma unroll
    for (int off = 16; off; off >>= 1) {
      la += __shfl_xor(la, off, 32);
      lv += __shfl_xor(lv, off, 32);
    }
    float pA = 1.f / (1.f + __expf((lv - la) * scale));
    float pV = 1.f - pA;
    size_t orow = ((size_t)(b * NSEN + s) * NSEG + g) * D_MODEL + h * DK;
#pragma unroll
    for (int e = 0; e < 4; ++e) {
      int d = l + e * 32;
      ctx[orow + d] = f2bf(pA * sk[2][h * DK + d] + pV * sk[3][h * DK + d]);
    }
  }
}

extern "C" void kernel_launch(void* const* d_in, const int* in_sizes, int n_in,
                              void* d_out, int out_size, void* d_ws, size_t ws_size,
                              hipStream_t stream) {
  const float* A  = (const float*)d_in[0];
  const float* V  = (const float*)d_in[1];
  const float* S  = (const float*)d_in[2];
  const float* wA = (const float*)d_in[3];  const float* bA = (const float*)d_in[4];
  const float* wV = (const float*)d_in[5];  const float* bV = (const float*)d_in[6];
  const float* wS = (const float*)d_in[7];  const float* bS = (const float*)d_in[8];
  const float* wq = (const float*)d_in[9];  const float* bq = (const float*)d_in[10];
  const float* wk = (const float*)d_in[11]; const float* bk = (const float*)d_in[12];
  const float* wv = (const float*)d_in[13]; const float* bv = (const float*)d_in[14];
  const float* w1 = (const float*)d_in[15]; const float* b1 = (const float*)d_in[16];
  const float* w2 = (const float*)d_in[17]; const float* b2 = (const float*)d_in[18];

  const int nAV = BS * NSEG * D_MODEL;   // 1,048,576
  const int nS  = BS * NSEN * D_MODEL;   // 524,288
  const int nW  = D_MODEL * D_MODEL;     // 1,048,576
  const int nCT = BS * NSEN * NSEG * D_MODEL;  // 33,554,432

  char* ws = (char*)d_ws;
  size_t off = 0;
  auto carve = [&](size_t elems) {
    unsigned short* p = (unsigned short*)(ws + off);
    off += elems * sizeof(unsigned short);
    return p;
  };
  unsigned short* bwA = carve(nW);
  unsigned short* bwV = carve(nW);
  unsigned short* bwS = carve(nW);
  unsigned short* bwq = carve(nW);
  unsigned short* bwk = carve(nW);
  unsigned short* bwv = carve(nW);
  unsigned short* bw1 = carve(nW);
  unsigned short* bw2 = carve(nW);
  unsigned short* xA  = carve(nAV);
  unsigned short* xV  = carve(nAV);
  unsigned short* xS  = carve(nS);
  unsigned short* A1V1 = carve(2 * nAV);   // A1 rows then V1 rows (M=2048)
  unsigned short* A1 = A1V1;
  unsigned short* V1 = A1V1 + nAV;
  unsigned short* S1  = carve(nS);
  unsigned short* qb  = carve(nS);
  unsigned short* kAV = carve(2 * nAV);    // kA rows then kV rows
  unsigned short* vAV = carve(2 * nAV);
  unsigned short* ctx = carve(nCT);        // 64MB
  unsigned short* hid = carve(nCT);        // 64MB
  (void)ws_size; (void)n_in; (void)in_sizes; (void)out_size;

  auto cvt = [&](const float* src, unsigned short* dst, int n) {
    int n4 = n / 4;
    f2b_kernel<<<dim3((n4 + 255) / 256), dim3(256), 0, stream>>>(src, dst, n4);
  };
  // converts
  cvt(A, xA, nAV); cvt(V, xV, nAV); cvt(S, xS, nS);
  cvt(wA, bwA, nW); cvt(wV, bwV, nW); cvt(wS, bwS, nW); cvt(wq, bwq, nW);
  cvt(wk, bwk, nW); cvt(wv, bwv, nW); cvt(w1, bw1, nW); cvt(w2, bw2, nW);

  // input projections
  gemm_bt<0, 1><<<dim3(8, 8),   256, 0, stream>>>(xA, bwA, bA, A1, 1024, 1024, 1024);
  gemm_bt<0, 1><<<dim3(8, 8),   256, 0, stream>>>(xV, bwV, bV, V1, 1024, 1024, 1024);
  gemm_bt<0, 1><<<dim3(8, 4),   256, 0, stream>>>(xS, bwS, bS, S1, 512, 1024, 1024);
  // q/k/v projections (k,v batched over [A1;V1])
  gemm_bt<0, 1><<<dim3(8, 4),   256, 0, stream>>>(S1, bwq, bq, qb, 512, 1024, 1024);
  gemm_bt<0, 1><<<dim3(8, 16),  256, 0, stream>>>(A1V1, bwk, bk, kAV, 2048, 1024, 1024);
  gemm_bt<0, 1><<<dim3(8, 16),  256, 0, stream>>>(A1V1, bwv, bv, vAV, 2048, 1024, 1024);
  // attention over A/V axis
  attn_kernel<<<dim3(BS * NSEG), dim3(256), 0, stream>>>(qb, kAV, kAV + nAV,
                                                         vAV, vAV + nAV, ctx);
  // positionwise FF
  gemm_bt<1, 1><<<dim3(8, 256), 256, 0, stream>>>(ctx, bw1, b1, hid, 32768, 1024, 1024);
  gemm_bt<0, 0><<<dim3(8, 256), 256, 0, stream>>>(hid, bw2, b2, d_out, 32768, 1024, 1024);
}

// Round 2
// 333.739 us; speedup vs baseline: 1.2866x; 1.2866x over previous
//
#include <hip/hip_runtime.h>
#include <stdint.h>

// ---------------------------------------------------------------------------
// AVFusion round 2: algebraic elimination of FF1.
//   hid[b,s,g,n] = relu(b1[n] + sum_h pA[b,s,g,h]*UA[b,g,h,n] + pV*UV[b,g,h,n])
//   UA[b,g,h,n]  = vA[b,g,h*128:]·w1[n,h*128:]   (batched small GEMM, 4.3 GF)
// This removes FF1's 68.7 GF GEMM (123us) and the 64MB ctx round-trip.
// ---------------------------------------------------------------------------

#define D_MODEL 1024
#define N_HEAD  8
#define DK      128
#define BS      16
#define NSEG    64
#define NSEN    32

typedef __attribute__((ext_vector_type(8))) __bf16 bf16x8;
typedef __attribute__((ext_vector_type(8))) unsigned short u16x8;
typedef __attribute__((ext_vector_type(4))) float f32x4;

__device__ __forceinline__ float bf2f(unsigned short b) {
  union { unsigned int u; float f; } x; x.u = ((unsigned int)b) << 16; return x.f;
}
__device__ __forceinline__ unsigned short f2bf(float f) {
  union { float f; unsigned int u; } x; x.f = f;
  unsigned int u = x.u;
  unsigned int r = (u + 0x7fffu + ((u >> 16) & 1u)) >> 16;  // RNE
  return (unsigned short)r;
}

// fp32 -> bf16 conversion, vectorized by 4
__global__ __launch_bounds__(256)
void f2b_kernel(const float* __restrict__ in, unsigned short* __restrict__ out, int n4) {
  int i = blockIdx.x * 256 + threadIdx.x;
  if (i >= n4) return;
  float4 v = reinterpret_cast<const float4*>(in)[i];
  ushort4 o;
  o.x = f2bf(v.x); o.y = f2bf(v.y); o.z = f2bf(v.z); o.w = f2bf(v.w);
  reinterpret_cast<ushort4*>(out)[i] = o;
}

// fused convert of the 8 (1024x1024) weight matrices: 1024 blocks per weight
struct WConv { const float* s[8]; unsigned short* d[8]; };
__global__ __launch_bounds__(256)
void wconv_kernel(WConv p) {
  int w = blockIdx.x >> 10;                 // weight index 0..7
  int i = (blockIdx.x & 1023) * 256 + threadIdx.x;  // 0..262143 (n4)
  float4 v = reinterpret_cast<const float4*>(p.s[w])[i];
  ushort4 o;
  o.x = f2bf(v.x); o.y = f2bf(v.y); o.z = f2bf(v.z); o.w = f2bf(v.w);
  reinterpret_cast<ushort4*>(p.d[w])[i] = o;
}

// async global->LDS, 16B per lane
__device__ __forceinline__ void g2l16(const void* g, void* l) {
  __builtin_amdgcn_global_load_lds(
      (const __attribute__((address_space(1))) void*)g,
      (__attribute__((address_space(3))) void*)l, 16, 0, 0);
}

// C[M,N] = act(A[M,K] @ B[N,K]^T + bias). 128x128 tile, BK=32, 4 waves.
// 1D grid (nbx*nby blocks, %8==0) with bijective XCD swizzle.
template<int RELU, int BF16OUT>
__global__ __launch_bounds__(256)
void gemm_bt(const unsigned short* __restrict__ A, const unsigned short* __restrict__ B,
             const float* __restrict__ bias, void* __restrict__ Cout,
             int M, int N, int K, int nbx) {
  __shared__ __align__(16) unsigned short lA[128 * 32];
  __shared__ __align__(16) unsigned short lB[128 * 32];

  // XCD-aware swizzle: contiguous chunk of output tiles per XCD (grid%8==0)
  const int nwg = gridDim.x;
  const int chunk = nwg >> 3;
  const int sw = (blockIdx.x & 7) * chunk + (blockIdx.x >> 3);
  const int m0 = (sw / nbx) * 128, n0 = (sw % nbx) * 128;

  const int t = threadIdx.x;
  const int lane = t & 63, wv = t >> 6;
  const int wrow = (wv >> 1) * 64, wcol = (wv & 1) * 64;
  const int fr = lane & 15;        // row/col within fragment
  const int kg = lane >> 4;        // k-group (8 elems each)

  f32x4 acc[4][4] = {};

  const int r  = t >> 2;           // staging row 0..63
  const int c8 = (t & 3) * 8;      // staging k-chunk
  const unsigned short* ga = A + (size_t)(m0 + r) * K + c8;
  const unsigned short* gb = B + (size_t)(n0 + r) * K + c8;

  for (int k0 = 0; k0 < K; k0 += 32) {
    __syncthreads();
    g2l16(ga + k0,          &lA[t * 8]);
    g2l16(ga + k0 + 64 * K, &lA[2048 + t * 8]);
    g2l16(gb + k0,          &lB[t * 8]);
    g2l16(gb + k0 + 64 * K, &lB[2048 + t * 8]);
    __syncthreads();

    u16x8 af[4], bg_[4];
#pragma unroll
    for (int mi = 0; mi < 4; ++mi)
      af[mi] = *reinterpret_cast<const u16x8*>(&lA[(wrow + mi * 16 + fr) * 32 + kg * 8]);
#pragma unroll
    for (int ni = 0; ni < 4; ++ni)
      bg_[ni] = *reinterpret_cast<const u16x8*>(&lB[(wcol + ni * 16 + fr) * 32 + kg * 8]);
#pragma unroll
    for (int mi = 0; mi < 4; ++mi)
#pragma unroll
      for (int ni = 0; ni < 4; ++ni)
        acc[mi][ni] = __builtin_amdgcn_mfma_f32_16x16x32_bf16(
            __builtin_bit_cast(bf16x8, af[mi]), __builtin_bit_cast(bf16x8, bg_[ni]),
            acc[mi][ni], 0, 0, 0);
  }

  // C/D layout: col = lane&15, row = (lane>>4)*4 + j  [learn_hip m89/m91]
  const int rg = kg * 4;
#pragma unroll
  for (int ni = 0; ni < 4; ++ni) {
    const int gn = n0 + wcol + ni * 16 + fr;
    const float bv = bias ? bias[gn] : 0.0f;
#pragma unroll
    for (int mi = 0; mi < 4; ++mi) {
      const int gm = m0 + wrow + mi * 16 + rg;
#pragma unroll
      for (int j = 0; j < 4; ++j) {
        float v = acc[mi][ni][j] + bv;
        if (RELU) v = v > 0.f ? v : 0.f;
        if (BF16OUT)
          reinterpret_cast<unsigned short*>(Cout)[(size_t)(gm + j) * N + gn] = f2bf(v);
        else
          reinterpret_cast<float*>(Cout)[(size_t)(gm + j) * N + gn] = v;
      }
    }
  }
}

// UA/UV: per (tensor,head) GEMM. C[bg, n] = vX[bg, h*128+d] * w1[n, h*128+d].
// vAV: [2][1024][1024] bf16 (A rows then V rows). UAV: [2][1024][8][1024] bf16.
// grid (8 nblk, 8 mblk, 16 = tensor*8+h). K=128, lda=ldb=1024, ldc=8192.
__global__ __launch_bounds__(256)
void uav_gemm(const unsigned short* __restrict__ vAV, const unsigned short* __restrict__ w1,
              unsigned short* __restrict__ UAV) {
  __shared__ __align__(16) unsigned short lA[128 * 32];
  __shared__ __align__(16) unsigned short lB[128 * 32];

  const int zb = blockIdx.z;
  const int tensor = zb >> 3, h = zb & 7;
  const unsigned short* Ab = vAV + (size_t)tensor * (1024 * 1024) + h * 128;
  const unsigned short* Bb = w1 + h * 128;
  unsigned short* Cb = UAV + (size_t)tensor * (1024 * 8192) + h * 1024;

  const int t = threadIdx.x;
  const int m0 = blockIdx.y * 128, n0 = blockIdx.x * 128;
  const int lane = t & 63, wv = t >> 6;
  const int wrow = (wv >> 1) * 64, wcol = (wv & 1) * 64;
  const int fr = lane & 15, kg = lane >> 4;

  f32x4 acc[4][4] = {};

  const int r  = t >> 2;
  const int c8 = (t & 3) * 8;
  const unsigned short* ga = Ab + (size_t)(m0 + r) * 1024 + c8;
  const unsigned short* gb = Bb + (size_t)(n0 + r) * 1024 + c8;

  for (int k0 = 0; k0 < 128; k0 += 32) {
    __syncthreads();
    g2l16(ga + k0,             &lA[t * 8]);
    g2l16(ga + k0 + 64 * 1024, &lA[2048 + t * 8]);
    g2l16(gb + k0,             &lB[t * 8]);
    g2l16(gb + k0 + 64 * 1024, &lB[2048 + t * 8]);
    __syncthreads();

    u16x8 af[4], bg_[4];
#pragma unroll
    for (int mi = 0; mi < 4; ++mi)
      af[mi] = *reinterpret_cast<const u16x8*>(&lA[(wrow + mi * 16 + fr) * 32 + kg * 8]);
#pragma unroll
    for (int ni = 0; ni < 4; ++ni)
      bg_[ni] = *reinterpret_cast<const u16x8*>(&lB[(wcol + ni * 16 + fr) * 32 + kg * 8]);
#pragma unroll
    for (int mi = 0; mi < 4; ++mi)
#pragma unroll
      for (int ni = 0; ni < 4; ++ni)
        acc[mi][ni] = __builtin_amdgcn_mfma_f32_16x16x32_bf16(
            __builtin_bit_cast(bf16x8, af[mi]), __builtin_bit_cast(bf16x8, bg_[ni]),
            acc[mi][ni], 0, 0, 0);
  }

  const int rg = kg * 4;
#pragma unroll
  for (int ni = 0; ni < 4; ++ni) {
    const int gn = n0 + wcol + ni * 16 + fr;
#pragma unroll
    for (int mi = 0; mi < 4; ++mi) {
      const int gm = m0 + wrow + mi * 16 + rg;
#pragma unroll
      for (int j = 0; j < 4; ++j)
        Cb[(size_t)(gm + j) * 8192 + gn] = f2bf(acc[mi][ni][j]);
    }
  }
}

// Scores only: pA[b,s,g,h] = sigmoid((q.kA - q.kV)/sqrt(128)). Block per (b,g).
__global__ __launch_bounds__(256)
void score_kernel(const unsigned short* __restrict__ q,
                  const unsigned short* __restrict__ kAV,
                  float* __restrict__ pA) {
  const int bg = blockIdx.x;           // b*64 + g
  const int b = bg >> 6, g = bg & 63;
  __shared__ float sk[2][D_MODEL];
  const size_t rowA = (size_t)bg * D_MODEL;
  const size_t rowV = rowA + (size_t)BS * NSEG * D_MODEL;
  for (int i = threadIdx.x; i < D_MODEL; i += 256) {
    sk[0][i] = bf2f(kAV[rowA + i]);
    sk[1][i] = bf2f(kAV[rowV + i]);
  }
  __syncthreads();

  const int h = threadIdx.x >> 5;
  const int l = threadIdx.x & 31;
  const float scale = 0.08838834764831845f;  // 1/sqrt(128)

  for (int s = 0; s < NSEN; ++s) {
    const unsigned short* pq = q + ((size_t)(b * NSEN + s)) * D_MODEL + h * DK;
    float la = 0.f, lv = 0.f;
#pragma unroll
    for (int e = 0; e < 4; ++e) {
      int d = l + e * 32;
      float qv = bf2f(pq[d]);
      la += qv * sk[0][h * DK + d];
      lv += qv * sk[1][h * DK + d];
    }
#pragma unroll
    for (int off = 16; off; off >>= 1) {
      la += __shfl_xor(la, off, 32);
      lv += __shfl_xor(lv, off, 32);
    }
    if (l == 0) {
      float p = 1.f / (1.f + __expf((lv - la) * scale));
      pA[((size_t)(b * NSEN + s) * NSEG + g) * N_HEAD + h] = p;
    }
  }
}

// hid[b,s,g,n] = relu(b1[n] + sum_h pA*UA[h][n] + (1-pA)*UV[h][n])
//             = relu(b1[n] + sumUV[n] + sum_h pA[h]*(UA[h][n]-UV[h][n]))
// Block per (b,g); thread owns 4 consecutive n; dU/sUV live in registers
// across the 32-sentence loop.
__global__ __launch_bounds__(256)
void hid_asm_kernel(const unsigned short* __restrict__ UAV,
                    const float* __restrict__ pA, const float* __restrict__ b1,
                    unsigned short* __restrict__ hid) {
  const int bg = blockIdx.x;
  const int b = bg >> 6, g = bg & 63;
  const int n0 = threadIdx.x * 4;

  const unsigned short* ua = UAV + (size_t)bg * 8192 + n0;
  const unsigned short* uv = ua + (size_t)1024 * 8192;

  float dU[N_HEAD][4];
  float base[4];
#pragma unroll
  for (int j = 0; j < 4; ++j) base[j] = b1[n0 + j];
#pragma unroll
  for (int h = 0; h < N_HEAD; ++h) {
    ushort4 a4 = *reinterpret_cast<const ushort4*>(ua + h * 1024);
    ushort4 v4 = *reinterpret_cast<const ushort4*>(uv + h * 1024);
    float va[4] = {bf2f(a4.x), bf2f(a4.y), bf2f(a4.z), bf2f(a4.w)};
    float vv[4] = {bf2f(v4.x), bf2f(v4.y), bf2f(v4.z), bf2f(v4.w)};
#pragma unroll
    for (int j = 0; j < 4; ++j) { dU[h][j] = va[j] - vv[j]; base[j] += vv[j]; }
  }

  for (int s = 0; s < NSEN; ++s) {
    const float* pp = pA + ((size_t)(b * NSEN + s) * NSEG + g) * N_HEAD;
    float4 p0 = reinterpret_cast<const float4*>(pp)[0];
    float4 p1 = reinterpret_cast<const float4*>(pp)[1];
    const float pa[8] = {p0.x, p0.y, p0.z, p0.w, p1.x, p1.y, p1.z, p1.w};
    float val[4] = {base[0], base[1], base[2], base[3]};
#pragma unroll
    for (int h = 0; h < N_HEAD; ++h)
#pragma unroll
      for (int j = 0; j < 4; ++j) val[j] = fmaf(pa[h], dU[h][j], val[j]);
    ushort4 o;
    o.x = f2bf(val[0] > 0.f ? val[0] : 0.f);
    o.y = f2bf(val[1] > 0.f ? val[1] : 0.f);
    o.z = f2bf(val[2] > 0.f ? val[2] : 0.f);
    o.w = f2bf(val[3] > 0.f ? val[3] : 0.f);
    size_t orow = ((size_t)(b * NSEN + s) * NSEG + g) * D_MODEL + n0;
    *reinterpret_cast<ushort4*>(hid + orow) = o;
  }
}

extern "C" void kernel_launch(void* const* d_in, const int* in_sizes, int n_in,
                              void* d_out, int out_size, void* d_ws, size_t ws_size,
                              hipStream_t stream) {
  const float* A  = (const float*)d_in[0];
  const float* V  = (const float*)d_in[1];
  const float* S  = (const float*)d_in[2];
  const float* wA = (const float*)d_in[3];  const float* bA = (const float*)d_in[4];
  const float* wV = (const float*)d_in[5];  const float* bV = (const float*)d_in[6];
  const float* wS = (const float*)d_in[7];  const float* bS = (const float*)d_in[8];
  const float* wq = (const float*)d_in[9];  const float* bq = (const float*)d_in[10];
  const float* wk = (const float*)d_in[11]; const float* bk = (const float*)d_in[12];
  const float* wv = (const float*)d_in[13]; const float* bv = (const float*)d_in[14];
  const float* w1 = (const float*)d_in[15]; const float* b1 = (const float*)d_in[16];
  const float* w2 = (const float*)d_in[17]; const float* b2 = (const float*)d_in[18];

  const int nAV = BS * NSEG * D_MODEL;         // 1,048,576
  const int nS  = BS * NSEN * D_MODEL;         // 524,288
  const int nW  = D_MODEL * D_MODEL;           // 1,048,576
  const int nCT = BS * NSEN * NSEG * D_MODEL;  // 33,554,432
  const int nU  = 2 * 1024 * 8 * 1024;         // 16,777,216

  char* ws = (char*)d_ws;
  size_t off = 0;
  auto carve = [&](size_t elems) {
    unsigned short* p = (unsigned short*)(ws + off);
    off += elems * sizeof(unsigned short);
    return p;
  };
  unsigned short* bwA = carve(nW);
  unsigned short* bwV = carve(nW);
  unsigned short* bwS = carve(nW);
  unsigned short* bwq = carve(nW);
  unsigned short* bwk = carve(nW);
  unsigned short* bwv = carve(nW);
  unsigned short* bw1 = carve(nW);
  unsigned short* bw2 = carve(nW);
  unsigned short* xA  = carve(nAV);
  unsigned short* xV  = carve(nAV);
  unsigned short* xS  = carve(nS);
  unsigned short* A1V1 = carve(2 * nAV);   // A1 rows then V1 rows (M=2048)
  unsigned short* S1  = carve(nS);
  unsigned short* qb  = carve(nS);
  unsigned short* kAV = carve(2 * nAV);    // kA rows then kV rows
  unsigned short* vAV = carve(2 * nAV);    // vA rows then vV rows
  unsigned short* UAV = carve(nU);         // [2][1024][8][1024]
  unsigned short* hid = carve(nCT);        // 64MB
  float* pAbuf = (float*)(ws + off);
  off += (size_t)BS * NSEN * NSEG * N_HEAD * sizeof(float);
  (void)ws_size; (void)n_in; (void)in_sizes; (void)out_size;

  auto cvt = [&](const float* src, unsigned short* dst, int n) {
    int n4 = n / 4;
    f2b_kernel<<<dim3((n4 + 255) / 256), dim3(256), 0, stream>>>(src, dst, n4);
  };
  // activation converts + fused weight convert
  cvt(A, xA, nAV); cvt(V, xV, nAV); cvt(S, xS, nS);
  WConv wc;
  wc.s[0] = wA; wc.d[0] = bwA;  wc.s[1] = wV; wc.d[1] = bwV;
  wc.s[2] = wS; wc.d[2] = bwS;  wc.s[3] = wq; wc.d[3] = bwq;
  wc.s[4] = wk; wc.d[4] = bwk;  wc.s[5] = wv; wc.d[5] = bwv;
  wc.s[6] = w1; wc.d[6] = bw1;  wc.s[7] = w2; wc.d[7] = bw2;
  wconv_kernel<<<dim3(8 * 1024), dim3(256), 0, stream>>>(wc);

  // input projections (1D grid + XCD swizzle; nbx = N/128 = 8)
  gemm_bt<0, 1><<<dim3(64),   256, 0, stream>>>(xA, bwA, bA, A1V1,       1024, 1024, 1024, 8);
  gemm_bt<0, 1><<<dim3(64),   256, 0, stream>>>(xV, bwV, bV, A1V1 + nAV, 1024, 1024, 1024, 8);
  gemm_bt<0, 1><<<dim3(32),   256, 0, stream>>>(xS, bwS, bS, S1,          512, 1024, 1024, 8);
  // q/k/v projections (k,v batched over [A1;V1])
  gemm_bt<0, 1><<<dim3(32),   256, 0, stream>>>(S1,   bwq, bq, qb,        512, 1024, 1024, 8);
  gemm_bt<0, 1><<<dim3(128),  256, 0, stream>>>(A1V1, bwk, bk, kAV,      2048, 1024, 1024, 8);
  gemm_bt<0, 1><<<dim3(128),  256, 0, stream>>>(A1V1, bwv, bv, vAV,      2048, 1024, 1024, 8);
  // attention scores (pA only)
  score_kernel<<<dim3(BS * NSEG), dim3(256), 0, stream>>>(qb, kAV, pAbuf);
  // UA/UV: batched per (tensor, head) small GEMMs against w1 slices
  uav_gemm<<<dim3(8, 8, 16), dim3(256), 0, stream>>>(vAV, bw1, UAV);
  // assemble hid = relu(FF1) directly from pA and UA/UV
  hid_asm_kernel<<<dim3(BS * NSEG), dim3(256), 0, stream>>>(UAV, pAbuf, b1, hid);
  // FF2
  gemm_bt<0, 0><<<dim3(2048), 256, 0, stream>>>(hid, bw2, b2, d_out, 32768, 1024, 1024, 8);
}

// Round 3
// 322.237 us; speedup vs baseline: 1.3326x; 1.0357x over previous
//
#include <hip/hip_runtime.h>
#include <stdint.h>

// ---------------------------------------------------------------------------
// AVFusion round 3: FF2 ported to the 256x256 8-phase schedule
// (T3+T4 counted vmcnt, T2 LDS XOR swizzle via pre-swizzled global source,
//  T5 setprio). Everything else as round 2.
// ---------------------------------------------------------------------------

#define D_MODEL 1024
#define N_HEAD  8
#define DK      128
#define BS      16
#define NSEG    64
#define NSEN    32

typedef __attribute__((ext_vector_type(8))) __bf16 bf16x8;
typedef __attribute__((ext_vector_type(8))) unsigned short u16x8;
typedef __attribute__((ext_vector_type(4))) float f32x4;

__device__ __forceinline__ float bf2f(unsigned short b) {
  union { unsigned int u; float f; } x; x.u = ((unsigned int)b) << 16; return x.f;
}
__device__ __forceinline__ unsigned short f2bf(float f) {
  union { float f; unsigned int u; } x; x.f = f;
  unsigned int u = x.u;
  unsigned int r = (u + 0x7fffu + ((u >> 16) & 1u)) >> 16;  // RNE
  return (unsigned short)r;
}

// fp32 -> bf16 conversion, vectorized by 4
__global__ __launch_bounds__(256)
void f2b_kernel(const float* __restrict__ in, unsigned short* __restrict__ out, int n4) {
  int i = blockIdx.x * 256 + threadIdx.x;
  if (i >= n4) return;
  float4 v = reinterpret_cast<const float4*>(in)[i];
  ushort4 o;
  o.x = f2bf(v.x); o.y = f2bf(v.y); o.z = f2bf(v.z); o.w = f2bf(v.w);
  reinterpret_cast<ushort4*>(out)[i] = o;
}

// fused convert of the 8 (1024x1024) weight matrices
struct WConv { const float* s[8]; unsigned short* d[8]; };
__global__ __launch_bounds__(256)
void wconv_kernel(WConv p) {
  int w = blockIdx.x >> 10;
  int i = (blockIdx.x & 1023) * 256 + threadIdx.x;
  float4 v = reinterpret_cast<const float4*>(p.s[w])[i];
  ushort4 o;
  o.x = f2bf(v.x); o.y = f2bf(v.y); o.z = f2bf(v.z); o.w = f2bf(v.w);
  reinterpret_cast<ushort4*>(p.d[w])[i] = o;
}

// async global->LDS, 16B per lane
__device__ __forceinline__ void g2l16(const void* g, void* l) {
  __builtin_amdgcn_global_load_lds(
      (const __attribute__((address_space(1))) void*)g,
      (__attribute__((address_space(3))) void*)l, 16, 0, 0);
}

// ========================= 2-phase 128x128 GEMM (round-2) ==================
template<int RELU, int BF16OUT>
__global__ __launch_bounds__(256)
void gemm_bt(const unsigned short* __restrict__ A, const unsigned short* __restrict__ B,
             const float* __restrict__ bias, void* __restrict__ Cout,
             int M, int N, int K, int nbx) {
  __shared__ __align__(16) unsigned short lA[128 * 32];
  __shared__ __align__(16) unsigned short lB[128 * 32];

  const int nwg = gridDim.x;
  const int chunk = nwg >> 3;
  const int sw = (blockIdx.x & 7) * chunk + (blockIdx.x >> 3);
  const int m0 = (sw / nbx) * 128, n0 = (sw % nbx) * 128;

  const int t = threadIdx.x;
  const int lane = t & 63, wv = t >> 6;
  const int wrow = (wv >> 1) * 64, wcol = (wv & 1) * 64;
  const int fr = lane & 15;
  const int kg = lane >> 4;

  f32x4 acc[4][4] = {};

  const int r  = t >> 2;
  const int c8 = (t & 3) * 8;
  const unsigned short* ga = A + (size_t)(m0 + r) * K + c8;
  const unsigned short* gb = B + (size_t)(n0 + r) * K + c8;

  for (int k0 = 0; k0 < K; k0 += 32) {
    __syncthreads();
    g2l16(ga + k0,          &lA[t * 8]);
    g2l16(ga + k0 + 64 * K, &lA[2048 + t * 8]);
    g2l16(gb + k0,          &lB[t * 8]);
    g2l16(gb + k0 + 64 * K, &lB[2048 + t * 8]);
    __syncthreads();

    u16x8 af[4], bg_[4];
#pragma unroll
    for (int mi = 0; mi < 4; ++mi)
      af[mi] = *reinterpret_cast<const u16x8*>(&lA[(wrow + mi * 16 + fr) * 32 + kg * 8]);
#pragma unroll
    for (int ni = 0; ni < 4; ++ni)
      bg_[ni] = *reinterpret_cast<const u16x8*>(&lB[(wcol + ni * 16 + fr) * 32 + kg * 8]);
#pragma unroll
    for (int mi = 0; mi < 4; ++mi)
#pragma unroll
      for (int ni = 0; ni < 4; ++ni)
        acc[mi][ni] = __builtin_amdgcn_mfma_f32_16x16x32_bf16(
            __builtin_bit_cast(bf16x8, af[mi]), __builtin_bit_cast(bf16x8, bg_[ni]),
            acc[mi][ni], 0, 0, 0);
  }

  const int rg = kg * 4;
#pragma unroll
  for (int ni = 0; ni < 4; ++ni) {
    const int gn = n0 + wcol + ni * 16 + fr;
    const float bv = bias ? bias[gn] : 0.0f;
#pragma unroll
    for (int mi = 0; mi < 4; ++mi) {
      const int gm = m0 + wrow + mi * 16 + rg;
#pragma unroll
      for (int j = 0; j < 4; ++j) {
        float v = acc[mi][ni][j] + bv;
        if (RELU) v = v > 0.f ? v : 0.f;
        if (BF16OUT)
          reinterpret_cast<unsigned short*>(Cout)[(size_t)(gm + j) * N + gn] = f2bf(v);
        else
          reinterpret_cast<float*>(Cout)[(size_t)(gm + j) * N + gn] = v;
      }
    }
  }
}

// ========================= 8-phase 256x256 GEMM ============================
// C[M,N] = A[M,K] @ B[N,K]^T + bias. bf16 in, fp32 out. M%256==0, N%256==0,
// K%64==0, K/64 >= 3. 512 threads = 8 waves (2M x 4N), per-wave 128x64 out.
// LDS: 2 buffers x (A 256x64 + B 256x64) bf16 = 128 KiB, staged in wave-
// region-reordered halves so each half is LDS-read in exactly one phase:
//   A LDS row l = mh*128 + wr*64 + r   <-> global row wr*128 + mh*64 + r
//   B LDS row l = nh*128 + wc*32 + r   <-> global row wc*64  + nh*32 + r
// Slot swizzle (T2): reader uses slot s^(l&7); stage fetches global slot
// (T&7)^(l&7) into linear slot (T&7)  [rule #21: same involution both sides].
// Per K-tile 4 phases: P1 reads A-lo+B-lo, stages B-hi(t+1); P2 reads
// A-hi+B-hi, stages A-lo(t+2); P3 MFMA-only, stages B-lo(t+2); P4 MFMA-only,
// stages A-hi(t+2) + vmcnt(6)  -> 3 half-tiles (6 loads) in flight, and each
// overwrite lands >=1 trailing-barrier after its slot's last read.
__global__ __launch_bounds__(512, 2)
void gemm8p_bt(const unsigned short* __restrict__ A, const unsigned short* __restrict__ B,
               const float* __restrict__ bias, float* __restrict__ C,
               int M, int N, int K, int nbx) {
  __shared__ __align__(16) unsigned short lds[2][2][256][64];

  const int nwg = gridDim.x;
  const int sw = (blockIdx.x & 7) * (nwg >> 3) + (blockIdx.x >> 3);
  const int m0 = (sw / nbx) * 256, n0 = (sw % nbx) * 256;

  const int T = threadIdx.x;
  const int lane = T & 63, wave = T >> 6;
  const int wr = wave >> 2, wc = wave & 3;
  const int fr = lane & 15, kg = lane >> 4;
  const int NT = K >> 6;

  // ---- staging constants ----
  const int sgs = (T & 7) ^ ((T >> 3) & 7);        // global k-slot for stage
  int grA[2][2], grB[2][2];
#pragma unroll
  for (int mh = 0; mh < 2; ++mh)
#pragma unroll
    for (int c = 0; c < 2; ++c) {
      int l = mh * 128 + c * 64 + (T >> 3);
      grA[mh][c] = ((l >> 6) & 1) * 128 + (l >> 7) * 64 + (l & 63);
      grB[mh][c] = ((l >> 5) & 3) * 64  + (l >> 7) * 32 + (l & 31);
    }
  const unsigned short* Abase = A + (size_t)m0 * K + sgs * 8;
  const unsigned short* Bbase = B + (size_t)n0 * K + sgs * 8;
  char* ldsc = (char*)&lds[0][0][0][0];

  auto stageA = [&](int buf, int mh, int t) {
#pragma unroll
    for (int c = 0; c < 2; ++c)
      g2l16(Abase + (size_t)grA[mh][c] * K + t * 64,
            ldsc + ((size_t)buf * 65536) + (mh * 128 + c * 64) * 128 + T * 16);
  };
  auto stageB = [&](int buf, int nh, int t) {
#pragma unroll
    for (int c = 0; c < 2; ++c)
      g2l16(Bbase + (size_t)grB[nh][c] * K + t * 64,
            ldsc + ((size_t)buf * 65536) + 32768 + (nh * 128 + c * 64) * 128 + T * 16);
  };

  // ---- read constants ----
  int koff[2];
#pragma unroll
  for (int kk = 0; kk < 2; ++kk) koff[kk] = ((kk * 4 + kg) ^ (fr & 7)) * 16;
  int lrA[8], lrB[4];
#pragma unroll
  for (int mi = 0; mi < 8; ++mi) lrA[mi] = ((mi >> 2) * 128 + wr * 64 + (mi & 3) * 16 + fr) * 128;
#pragma unroll
  for (int ni = 0; ni < 4; ++ni) lrB[ni] = ((ni >> 1) * 128 + wc * 32 + (ni & 1) * 16 + fr) * 128;

  auto rdA = [&](int buf, int mi, int kk) -> u16x8 {
    return *reinterpret_cast<const u16x8*>(ldsc + (size_t)buf * 65536 + lrA[mi] + koff[kk]);
  };
  auto rdB = [&](int buf, int ni, int kk) -> u16x8 {
    return *reinterpret_cast<const u16x8*>(ldsc + (size_t)buf * 65536 + 32768 + lrB[ni] + koff[kk]);
  };

  f32x4 acc[8][4] = {};

  // ---- prologue: tile0 all 4 halves, tile1 A-lo,B-lo,A-hi ----
  stageA(0, 0, 0); stageB(0, 0, 0); stageA(0, 1, 0); stageB(0, 1, 0);
  if (NT > 1) { stageA(1, 0, 1); stageB(1, 0, 1); stageA(1, 1, 1); }
  asm volatile("s_waitcnt vmcnt(6)" ::: "memory");
  __builtin_amdgcn_s_barrier();

  u16x8 af0[4][2], af1[4][2], bf0[2][2], bf1[2][2];

  for (int t = 0; t < NT; ++t) {
    const int buf = t & 1;
    const bool st1 = (t + 1 < NT), st2 = (t + 2 < NT);

    // ---- P1: read A-lo + B-lo; stage B-hi(t+1) -> other buf ----
#pragma unroll
    for (int mi = 0; mi < 4; ++mi)
#pragma unroll
      for (int kk = 0; kk < 2; ++kk) af0[mi][kk] = rdA(buf, mi, kk);
#pragma unroll
    for (int ni = 0; ni < 2; ++ni)
#pragma unroll
      for (int kk = 0; kk < 2; ++kk) bf0[ni][kk] = rdB(buf, ni, kk);
    if (st1) stageB(buf ^ 1, 1, t + 1);
    __builtin_amdgcn_s_barrier();
    asm volatile("s_waitcnt lgkmcnt(0)" ::: "memory");
    __builtin_amdgcn_sched_barrier(0);
    __builtin_amdgcn_s_setprio(1);
#pragma unroll
    for (int mi = 0; mi < 4; ++mi)
#pragma unroll
      for (int ni = 0; ni < 2; ++ni)
#pragma unroll
        for (int kk = 0; kk < 2; ++kk)
          acc[mi][ni] = __builtin_amdgcn_mfma_f32_16x16x32_bf16(
              __builtin_bit_cast(bf16x8, af0[mi][kk]), __builtin_bit_cast(bf16x8, bf0[ni][kk]),
              acc[mi][ni], 0, 0, 0);
    __builtin_amdgcn_s_setprio(0);
    __builtin_amdgcn_s_barrier();

    // ---- P2: read A-hi + B-hi; stage A-lo(t+2) -> cur buf (read done P1) ----
#pragma unroll
    for (int mi = 0; mi < 4; ++mi)
#pragma unroll
      for (int kk = 0; kk < 2; ++kk) af1[mi][kk] = rdA(buf, mi + 4, kk);
#pragma unroll
    for (int ni = 0; ni < 2; ++ni)
#pragma unroll
      for (int kk = 0; kk < 2; ++kk) bf1[ni][kk] = rdB(buf, ni + 2, kk);
    if (st2) stageA(buf, 0, t + 2);
    __builtin_amdgcn_s_barrier();
    asm volatile("s_waitcnt lgkmcnt(0)" ::: "memory");
    __builtin_amdgcn_sched_barrier(0);
    __builtin_amdgcn_s_setprio(1);
#pragma unroll
    for (int mi = 0; mi < 4; ++mi)
#pragma unroll
      for (int ni = 0; ni < 2; ++ni)
#pragma unroll
        for (int kk = 0; kk < 2; ++kk)
          acc[mi][ni + 2] = __builtin_amdgcn_mfma_f32_16x16x32_bf16(
              __builtin_bit_cast(bf16x8, af0[mi][kk]), __builtin_bit_cast(bf16x8, bf1[ni][kk]),
              acc[mi][ni + 2], 0, 0, 0);
    __builtin_amdgcn_s_setprio(0);
    __builtin_amdgcn_s_barrier();

    // ---- P3: MFMA-only (A-hi x B-hi); stage B-lo(t+2) (read done P1) ----
    if (st2) stageB(buf, 0, t + 2);
    __builtin_amdgcn_s_barrier();
    __builtin_amdgcn_s_setprio(1);
#pragma unroll
    for (int mi = 0; mi < 4; ++mi)
#pragma unroll
      for (int ni = 0; ni < 2; ++ni)
#pragma unroll
        for (int kk = 0; kk < 2; ++kk)
          acc[mi + 4][ni + 2] = __builtin_amdgcn_mfma_f32_16x16x32_bf16(
              __builtin_bit_cast(bf16x8, af1[mi][kk]), __builtin_bit_cast(bf16x8, bf1[ni][kk]),
              acc[mi + 4][ni + 2], 0, 0, 0);
    __builtin_amdgcn_s_setprio(0);
    __builtin_amdgcn_s_barrier();

    // ---- P4: MFMA-only (A-hi x B-lo); stage A-hi(t+2) (read done P2) ----
    if (st2) stageA(buf, 1, t + 2);
    __builtin_amdgcn_s_barrier();
    __builtin_amdgcn_s_setprio(1);
#pragma unroll
    for (int mi = 0; mi < 4; ++mi)
#pragma unroll
      for (int ni = 0; ni < 2; ++ni)
#pragma unroll
        for (int kk = 0; kk < 2; ++kk)
          acc[mi + 4][ni] = __builtin_amdgcn_mfma_f32_16x16x32_bf16(
              __builtin_bit_cast(bf16x8, af1[mi][kk]), __builtin_bit_cast(bf16x8, bf0[ni][kk]),
              acc[mi + 4][ni], 0, 0, 0);
    __builtin_amdgcn_s_setprio(0);
    if (st2)       asm volatile("s_waitcnt vmcnt(6)" ::: "memory");
    else if (st1)  asm volatile("s_waitcnt vmcnt(0)" ::: "memory");
    __builtin_amdgcn_s_barrier();
  }

  // ---- epilogue ----
#pragma unroll
  for (int ni = 0; ni < 4; ++ni) {
    const int gn = n0 + wc * 64 + ni * 16 + fr;
    const float bv = bias[gn];
#pragma unroll
    for (int mi = 0; mi < 8; ++mi) {
      const int gm = m0 + wr * 128 + mi * 16 + kg * 4;
#pragma unroll
      for (int j = 0; j < 4; ++j)
        C[(size_t)(gm + j) * N + gn] = acc[mi][ni][j] + bv;
    }
  }
}

// ========================= small fused kernels (round-2) ===================
__global__ __launch_bounds__(256)
void uav_gemm(const unsigned short* __restrict__ vAV, const unsigned short* __restrict__ w1,
              unsigned short* __restrict__ UAV) {
  __shared__ __align__(16) unsigned short lA[128 * 32];
  __shared__ __align__(16) unsigned short lB[128 * 32];

  const int zb = blockIdx.z;
  const int tensor = zb >> 3, h = zb & 7;
  const unsigned short* Ab = vAV + (size_t)tensor * (1024 * 1024) + h * 128;
  const unsigned short* Bb = w1 + h * 128;
  unsigned short* Cb = UAV + (size_t)tensor * (1024 * 8192) + h * 1024;

  const int t = threadIdx.x;
  const int m0 = blockIdx.y * 128, n0 = blockIdx.x * 128;
  const int lane = t & 63, wv = t >> 6;
  const int wrow = (wv >> 1) * 64, wcol = (wv & 1) * 64;
  const int fr = lane & 15, kg = lane >> 4;

  f32x4 acc[4][4] = {};

  const int r  = t >> 2;
  const int c8 = (t & 3) * 8;
  const unsigned short* ga = Ab + (size_t)(m0 + r) * 1024 + c8;
  const unsigned short* gb = Bb + (size_t)(n0 + r) * 1024 + c8;

  for (int k0 = 0; k0 < 128; k0 += 32) {
    __syncthreads();
    g2l16(ga + k0,             &lA[t * 8]);
    g2l16(ga + k0 + 64 * 1024, &lA[2048 + t * 8]);
    g2l16(gb + k0,             &lB[t * 8]);
    g2l16(gb + k0 + 64 * 1024, &lB[2048 + t * 8]);
    __syncthreads();

    u16x8 af[4], bg_[4];
#pragma unroll
    for (int mi = 0; mi < 4; ++mi)
      af[mi] = *reinterpret_cast<const u16x8*>(&lA[(wrow + mi * 16 + fr) * 32 + kg * 8]);
#pragma unroll
    for (int ni = 0; ni < 4; ++ni)
      bg_[ni] = *reinterpret_cast<const u16x8*>(&lB[(wcol + ni * 16 + fr) * 32 + kg * 8]);
#pragma unroll
    for (int mi = 0; mi < 4; ++mi)
#pragma unroll
      for (int ni = 0; ni < 4; ++ni)
        acc[mi][ni] = __builtin_amdgcn_mfma_f32_16x16x32_bf16(
            __builtin_bit_cast(bf16x8, af[mi]), __builtin_bit_cast(bf16x8, bg_[ni]),
            acc[mi][ni], 0, 0, 0);
  }

  const int rg = kg * 4;
#pragma unroll
  for (int ni = 0; ni < 4; ++ni) {
    const int gn = n0 + wcol + ni * 16 + fr;
#pragma unroll
    for (int mi = 0; mi < 4; ++mi) {
      const int gm = m0 + wrow + mi * 16 + rg;
#pragma unroll
      for (int j = 0; j < 4; ++j)
        Cb[(size_t)(gm + j) * 8192 + gn] = f2bf(acc[mi][ni][j]);
    }
  }
}

__global__ __launch_bounds__(256)
void score_kernel(const unsigned short* __restrict__ q,
                  const unsigned short* __restrict__ kAV,
                  float* __restrict__ pA) {
  const int bg = blockIdx.x;
  const int b = bg >> 6, g = bg & 63;
  __shared__ float sk[2][D_MODEL];
  const size_t rowA = (size_t)bg * D_MODEL;
  const size_t rowV = rowA + (size_t)BS * NSEG * D_MODEL;
  for (int i = threadIdx.x; i < D_MODEL; i += 256) {
    sk[0][i] = bf2f(kAV[rowA + i]);
    sk[1][i] = bf2f(kAV[rowV + i]);
  }
  __syncthreads();

  const int h = threadIdx.x >> 5;
  const int l = threadIdx.x & 31;
  const float scale = 0.08838834764831845f;

  for (int s = 0; s < NSEN; ++s) {
    const unsigned short* pq = q + ((size_t)(b * NSEN + s)) * D_MODEL + h * DK;
    float la = 0.f, lv = 0.f;
#pragma unroll
    for (int e = 0; e < 4; ++e) {
      int d = l + e * 32;
      float qv = bf2f(pq[d]);
      la += qv * sk[0][h * DK + d];
      lv += qv * sk[1][h * DK + d];
    }
#pragma unroll
    for (int off = 16; off; off >>= 1) {
      la += __shfl_xor(la, off, 32);
      lv += __shfl_xor(lv, off, 32);
    }
    if (l == 0) {
      float p = 1.f / (1.f + __expf((lv - la) * scale));
      pA[((size_t)(b * NSEN + s) * NSEG + g) * N_HEAD + h] = p;
    }
  }
}

__global__ __launch_bounds__(256)
void hid_asm_kernel(const unsigned short* __restrict__ UAV,
                    const float* __restrict__ pA, const float* __restrict__ b1,
                    unsigned short* __restrict__ hid) {
  const int bg = blockIdx.x;
  const int b = bg >> 6, g = bg & 63;
  const int n0 = threadIdx.x * 4;

  const unsigned short* ua = UAV + (size_t)bg * 8192 + n0;
  const unsigned short* uv = ua + (size_t)1024 * 8192;

  float dU[N_HEAD][4];
  float base[4];
#pragma unroll
  for (int j = 0; j < 4; ++j) base[j] = b1[n0 + j];
#pragma unroll
  for (int h = 0; h < N_HEAD; ++h) {
    ushort4 a4 = *reinterpret_cast<const ushort4*>(ua + h * 1024);
    ushort4 v4 = *reinterpret_cast<const ushort4*>(uv + h * 1024);
    float va[4] = {bf2f(a4.x), bf2f(a4.y), bf2f(a4.z), bf2f(a4.w)};
    float vv[4] = {bf2f(v4.x), bf2f(v4.y), bf2f(v4.z), bf2f(v4.w)};
#pragma unroll
    for (int j = 0; j < 4; ++j) { dU[h][j] = va[j] - vv[j]; base[j] += vv[j]; }
  }

  for (int s = 0; s < NSEN; ++s) {
    const float* pp = pA + ((size_t)(b * NSEN + s) * NSEG + g) * N_HEAD;
    float4 p0 = reinterpret_cast<const float4*>(pp)[0];
    float4 p1 = reinterpret_cast<const float4*>(pp)[1];
    const float pa[8] = {p0.x, p0.y, p0.z, p0.w, p1.x, p1.y, p1.z, p1.w};
    float val[4] = {base[0], base[1], base[2], base[3]};
#pragma unroll
    for (int h = 0; h < N_HEAD; ++h)
#pragma unroll
      for (int j = 0; j < 4; ++j) val[j] = fmaf(pa[h], dU[h][j], val[j]);
    ushort4 o;
    o.x = f2bf(val[0] > 0.f ? val[0] : 0.f);
    o.y = f2bf(val[1] > 0.f ? val[1] : 0.f);
    o.z = f2bf(val[2] > 0.f ? val[2] : 0.f);
    o.w = f2bf(val[3] > 0.f ? val[3] : 0.f);
    size_t orow = ((size_t)(b * NSEN + s) * NSEG + g) * D_MODEL + n0;
    *reinterpret_cast<ushort4*>(hid + orow) = o;
  }
}

extern "C" void kernel_launch(void* const* d_in, const int* in_sizes, int n_in,
                              void* d_out, int out_size, void* d_ws, size_t ws_size,
                              hipStream_t stream) {
  const float* A  = (const float*)d_in[0];
  const float* V  = (const float*)d_in[1];
  const float* S  = (const float*)d_in[2];
  const float* wA = (const float*)d_in[3];  const float* bA = (const float*)d_in[4];
  const float* wV = (const float*)d_in[5];  const float* bV = (const float*)d_in[6];
  const float* wS = (const float*)d_in[7];  const float* bS = (const float*)d_in[8];
  const float* wq = (const float*)d_in[9];  const float* bq = (const float*)d_in[10];
  const float* wk = (const float*)d_in[11]; const float* bk = (const float*)d_in[12];
  const float* wv = (const float*)d_in[13]; const float* bv = (const float*)d_in[14];
  const float* w1 = (const float*)d_in[15]; const float* b1 = (const float*)d_in[16];
  const float* w2 = (const float*)d_in[17]; const float* b2 = (const float*)d_in[18];

  const int nAV = BS * NSEG * D_MODEL;
  const int nS  = BS * NSEN * D_MODEL;
  const int nW  = D_MODEL * D_MODEL;
  const int nCT = BS * NSEN * NSEG * D_MODEL;
  const int nU  = 2 * 1024 * 8 * 1024;

  char* ws = (char*)d_ws;
  size_t off = 0;
  auto carve = [&](size_t elems) {
    unsigned short* p = (unsigned short*)(ws + off);
    off += elems * sizeof(unsigned short);
    return p;
  };
  unsigned short* bwA = carve(nW);
  unsigned short* bwV = carve(nW);
  unsigned short* bwS = carve(nW);
  unsigned short* bwq = carve(nW);
  unsigned short* bwk = carve(nW);
  unsigned short* bwv = carve(nW);
  unsigned short* bw1 = carve(nW);
  unsigned short* bw2 = carve(nW);
  unsigned short* xA  = carve(nAV);
  unsigned short* xV  = carve(nAV);
  unsigned short* xS  = carve(nS);
  unsigned short* A1V1 = carve(2 * nAV);
  unsigned short* S1  = carve(nS);
  unsigned short* qb  = carve(nS);
  unsigned short* kAV = carve(2 * nAV);
  unsigned short* vAV = carve(2 * nAV);
  unsigned short* UAV = carve(nU);
  unsigned short* hid = carve(nCT);
  float* pAbuf = (float*)(ws + off);
  off += (size_t)BS * NSEN * NSEG * N_HEAD * sizeof(float);
  (void)ws_size; (void)n_in; (void)in_sizes; (void)out_size;

  auto cvt = [&](const float* src, unsigned short* dst, int n) {
    int n4 = n / 4;
    f2b_kernel<<<dim3((n4 + 255) / 256), dim3(256), 0, stream>>>(src, dst, n4);
  };
  cvt(A, xA, nAV); cvt(V, xV, nAV); cvt(S, xS, nS);
  WConv wc;
  wc.s[0] = wA; wc.d[0] = bwA;  wc.s[1] = wV; wc.d[1] = bwV;
  wc.s[2] = wS; wc.d[2] = bwS;  wc.s[3] = wq; wc.d[3] = bwq;
  wc.s[4] = wk; wc.d[4] = bwk;  wc.s[5] = wv; wc.d[5] = bwv;
  wc.s[6] = w1; wc.d[6] = bw1;  wc.s[7] = w2; wc.d[7] = bw2;
  wconv_kernel<<<dim3(8 * 1024), dim3(256), 0, stream>>>(wc);

  gemm_bt<0, 1><<<dim3(64),   256, 0, stream>>>(xA, bwA, bA, A1V1,       1024, 1024, 1024, 8);
  gemm_bt<0, 1><<<dim3(64),   256, 0, stream>>>(xV, bwV, bV, A1V1 + nAV, 1024, 1024, 1024, 8);
  gemm_bt<0, 1><<<dim3(32),   256, 0, stream>>>(xS, bwS, bS, S1,          512, 1024, 1024, 8);
  gemm_bt<0, 1><<<dim3(32),   256, 0, stream>>>(S1,   bwq, bq, qb,        512, 1024, 1024, 8);
  gemm_bt<0, 1><<<dim3(128),  256, 0, stream>>>(A1V1, bwk, bk, kAV,      2048, 1024, 1024, 8);
  gemm_bt<0, 1><<<dim3(128),  256, 0, stream>>>(A1V1, bwv, bv, vAV,      2048, 1024, 1024, 8);
  score_kernel<<<dim3(BS * NSEG), dim3(256), 0, stream>>>(qb, kAV, pAbuf);
  uav_gemm<<<dim3(8, 8, 16), dim3(256), 0, stream>>>(vAV, bw1, UAV);
  hid_asm_kernel<<<dim3(BS * NSEG), dim3(256), 0, stream>>>(UAV, pAbuf, b1, hid);
  // FF2 on the 8-phase 256^2 schedule: grid = (32768/256)*(1024/256) = 512
  gemm8p_bt<<<dim3(512), 512, 0, stream>>>(hid, bw2, b2, (float*)d_out,
                                           32768, 1024, 1024, 4);
}

// Round 4
// 198.316 us; speedup vs baseline: 2.1652x; 1.6249x over previous
//
#include <hip/hip_runtime.h>
#include <stdint.h>

// ---------------------------------------------------------------------------
// AVFusion round 4: collapse the small-kernel serial chain.
//  - one fused fp32->bf16 convert kernel (11 tensors)
//  - batched 64x128-tile GEMM for {A,V,S} proj (1 launch) and {q,k,v} (1 launch)
//  - score fused into hid assembly
//  - FF2 stays on the 8-phase 256^2 schedule (unchanged from round 3)
// 6 launches total.
// ---------------------------------------------------------------------------

#define D_MODEL 1024
#define N_HEAD  8
#define DK      128
#define BS      16
#define NSEG    64
#define NSEN    32

typedef __attribute__((ext_vector_type(8))) __bf16 bf16x8;
typedef __attribute__((ext_vector_type(8))) unsigned short u16x8;
typedef __attribute__((ext_vector_type(4))) float f32x4;

__device__ __forceinline__ float bf2f(unsigned short b) {
  union { unsigned int u; float f; } x; x.u = ((unsigned int)b) << 16; return x.f;
}
__device__ __forceinline__ unsigned short f2bf(float f) {
  union { float f; unsigned int u; } x; x.f = f;
  unsigned int u = x.u;
  unsigned int r = (u + 0x7fffu + ((u >> 16) & 1u)) >> 16;  // RNE
  return (unsigned short)r;
}

// async global->LDS, 16B per lane
__device__ __forceinline__ void g2l16(const void* g, void* l) {
  __builtin_amdgcn_global_load_lds(
      (const __attribute__((address_space(1))) void*)g,
      (__attribute__((address_space(3))) void*)l, 16, 0, 0);
}

// ===================== fused fp32->bf16 convert (11 tensors) ===============
struct CvtB { const float* s[11]; unsigned short* d[11]; int n4[11]; };
__global__ __launch_bounds__(256)
void cvtall_kernel(CvtB p) {
  const int z = blockIdx.y;
  const int i = blockIdx.x * 256 + threadIdx.x;
  if (i >= p.n4[z]) return;
  float4 v = reinterpret_cast<const float4*>(p.s[z])[i];
  ushort4 o;
  o.x = f2bf(v.x); o.y = f2bf(v.y); o.z = f2bf(v.z); o.w = f2bf(v.w);
  reinterpret_cast<ushort4*>(p.d[z])[i] = o;
}

// ===================== batched 64x128-tile GEMM ============================
// C[M,1024] = A[M,1024] @ B[1024,1024]^T + bias (bf16 out). Up to 3 segments
// per launch; nbx = 8 column tiles fixed. BM=64, BN=128, BK=32, 4 waves
// (wave w owns cols w*32..w*32+31). 12KB LDS -> multiple blocks/CU.
struct GSeg { const unsigned short* A; const unsigned short* B;
              const float* bias; unsigned short* C; };
struct GBatch { GSeg s[3]; int end[3]; };

__global__ __launch_bounds__(256)
void gemm64_bt(GBatch gb) {
  __shared__ __align__(16) unsigned short lA[64 * 32];
  __shared__ __align__(16) unsigned short lB[128 * 32];

  const int nwg = gridDim.x;                 // multiple of 8
  const int sw = (blockIdx.x & 7) * (nwg >> 3) + (blockIdx.x >> 3);
  int sgi = 0, base = 0;
  if (sw >= gb.end[0]) { sgi = 1; base = gb.end[0]; }
  if (sw >= gb.end[1]) { sgi = 2; base = gb.end[1]; }
  const GSeg sg = gb.s[sgi];
  const int st = sw - base;
  const int m0 = (st >> 3) * 64, n0 = (st & 7) * 128;

  const int t = threadIdx.x;
  const int lane = t & 63, w = t >> 6;
  const int fr = lane & 15, kg = lane >> 4;

  f32x4 acc[4][2] = {};

  const int r  = t >> 2;            // 0..63
  const int c8 = (t & 3) * 8;
  const unsigned short* ga  = sg.A + (size_t)(m0 + r) * 1024 + c8;
  const unsigned short* gbp = sg.B + (size_t)(n0 + r) * 1024 + c8;

  for (int k0 = 0; k0 < 1024; k0 += 32) {
    __syncthreads();
    g2l16(ga + k0,              &lA[t * 8]);
    g2l16(gbp + k0,             &lB[t * 8]);
    g2l16(gbp + k0 + 64 * 1024, &lB[2048 + t * 8]);
    __syncthreads();

    u16x8 af[4], bf[2];
#pragma unroll
    for (int mi = 0; mi < 4; ++mi)
      af[mi] = *reinterpret_cast<const u16x8*>(&lA[(mi * 16 + fr) * 32 + kg * 8]);
#pragma unroll
    for (int ni = 0; ni < 2; ++ni)
      bf[ni] = *reinterpret_cast<const u16x8*>(&lB[(w * 32 + ni * 16 + fr) * 32 + kg * 8]);
#pragma unroll
    for (int mi = 0; mi < 4; ++mi)
#pragma unroll
      for (int ni = 0; ni < 2; ++ni)
        acc[mi][ni] = __builtin_amdgcn_mfma_f32_16x16x32_bf16(
            __builtin_bit_cast(bf16x8, af[mi]), __builtin_bit_cast(bf16x8, bf[ni]),
            acc[mi][ni], 0, 0, 0);
  }

  // C/D layout: col = lane&15, row = (lane>>4)*4 + j
#pragma unroll
  for (int ni = 0; ni < 2; ++ni) {
    const int gn = n0 + w * 32 + ni * 16 + fr;
    const float bv = sg.bias[gn];
#pragma unroll
    for (int mi = 0; mi < 4; ++mi) {
      const int gm = m0 + mi * 16 + kg * 4;
#pragma unroll
      for (int j = 0; j < 4; ++j)
        sg.C[(size_t)(gm + j) * 1024 + gn] = f2bf(acc[mi][ni][j] + bv);
    }
  }
}

// ========================= 8-phase 256x256 GEMM (round-3, unchanged) =======
__global__ __launch_bounds__(512, 2)
void gemm8p_bt(const unsigned short* __restrict__ A, const unsigned short* __restrict__ B,
               const float* __restrict__ bias, float* __restrict__ C,
               int M, int N, int K, int nbx) {
  __shared__ __align__(16) unsigned short lds[2][2][256][64];

  const int nwg = gridDim.x;
  const int sw = (blockIdx.x & 7) * (nwg >> 3) + (blockIdx.x >> 3);
  const int m0 = (sw / nbx) * 256, n0 = (sw % nbx) * 256;

  const int T = threadIdx.x;
  const int lane = T & 63, wave = T >> 6;
  const int wr = wave >> 2, wc = wave & 3;
  const int fr = lane & 15, kg = lane >> 4;
  const int NT = K >> 6;

  const int sgs = (T & 7) ^ ((T >> 3) & 7);
  int grA[2][2], grB[2][2];
#pragma unroll
  for (int mh = 0; mh < 2; ++mh)
#pragma unroll
    for (int c = 0; c < 2; ++c) {
      int l = mh * 128 + c * 64 + (T >> 3);
      grA[mh][c] = ((l >> 6) & 1) * 128 + (l >> 7) * 64 + (l & 63);
      grB[mh][c] = ((l >> 5) & 3) * 64  + (l >> 7) * 32 + (l & 31);
    }
  const unsigned short* Abase = A + (size_t)m0 * K + sgs * 8;
  const unsigned short* Bbase = B + (size_t)n0 * K + sgs * 8;
  char* ldsc = (char*)&lds[0][0][0][0];

  auto stageA = [&](int buf, int mh, int t) {
#pragma unroll
    for (int c = 0; c < 2; ++c)
      g2l16(Abase + (size_t)grA[mh][c] * K + t * 64,
            ldsc + ((size_t)buf * 65536) + (mh * 128 + c * 64) * 128 + T * 16);
  };
  auto stageB = [&](int buf, int nh, int t) {
#pragma unroll
    for (int c = 0; c < 2; ++c)
      g2l16(Bbase + (size_t)grB[nh][c] * K + t * 64,
            ldsc + ((size_t)buf * 65536) + 32768 + (nh * 128 + c * 64) * 128 + T * 16);
  };

  int koff[2];
#pragma unroll
  for (int kk = 0; kk < 2; ++kk) koff[kk] = ((kk * 4 + kg) ^ (fr & 7)) * 16;
  int lrA[8], lrB[4];
#pragma unroll
  for (int mi = 0; mi < 8; ++mi) lrA[mi] = ((mi >> 2) * 128 + wr * 64 + (mi & 3) * 16 + fr) * 128;
#pragma unroll
  for (int ni = 0; ni < 4; ++ni) lrB[ni] = ((ni >> 1) * 128 + wc * 32 + (ni & 1) * 16 + fr) * 128;

  auto rdA = [&](int buf, int mi, int kk) -> u16x8 {
    return *reinterpret_cast<const u16x8*>(ldsc + (size_t)buf * 65536 + lrA[mi] + koff[kk]);
  };
  auto rdB = [&](int buf, int ni, int kk) -> u16x8 {
    return *reinterpret_cast<const u16x8*>(ldsc + (size_t)buf * 65536 + 32768 + lrB[ni] + koff[kk]);
  };

  f32x4 acc[8][4] = {};

  stageA(0, 0, 0); stageB(0, 0, 0); stageA(0, 1, 0); stageB(0, 1, 0);
  if (NT > 1) { stageA(1, 0, 1); stageB(1, 0, 1); stageA(1, 1, 1); }
  asm volatile("s_waitcnt vmcnt(6)" ::: "memory");
  __builtin_amdgcn_s_barrier();

  u16x8 af0[4][2], af1[4][2], bf0[2][2], bf1[2][2];

  for (int t = 0; t < NT; ++t) {
    const int buf = t & 1;
    const bool st1 = (t + 1 < NT), st2 = (t + 2 < NT);

#pragma unroll
    for (int mi = 0; mi < 4; ++mi)
#pragma unroll
      for (int kk = 0; kk < 2; ++kk) af0[mi][kk] = rdA(buf, mi, kk);
#pragma unroll
    for (int ni = 0; ni < 2; ++ni)
#pragma unroll
      for (int kk = 0; kk < 2; ++kk) bf0[ni][kk] = rdB(buf, ni, kk);
    if (st1) stageB(buf ^ 1, 1, t + 1);
    __builtin_amdgcn_s_barrier();
    asm volatile("s_waitcnt lgkmcnt(0)" ::: "memory");
    __builtin_amdgcn_sched_barrier(0);
    __builtin_amdgcn_s_setprio(1);
#pragma unroll
    for (int mi = 0; mi < 4; ++mi)
#pragma unroll
      for (int ni = 0; ni < 2; ++ni)
#pragma unroll
        for (int kk = 0; kk < 2; ++kk)
          acc[mi][ni] = __builtin_amdgcn_mfma_f32_16x16x32_bf16(
              __builtin_bit_cast(bf16x8, af0[mi][kk]), __builtin_bit_cast(bf16x8, bf0[ni][kk]),
              acc[mi][ni], 0, 0, 0);
    __builtin_amdgcn_s_setprio(0);
    __builtin_amdgcn_s_barrier();

#pragma unroll
    for (int mi = 0; mi < 4; ++mi)
#pragma unroll
      for (int kk = 0; kk < 2; ++kk) af1[mi][kk] = rdA(buf, mi + 4, kk);
#pragma unroll
    for (int ni = 0; ni < 2; ++ni)
#pragma unroll
      for (int kk = 0; kk < 2; ++kk) bf1[ni][kk] = rdB(buf, ni + 2, kk);
    if (st2) stageA(buf, 0, t + 2);
    __builtin_amdgcn_s_barrier();
    asm volatile("s_waitcnt lgkmcnt(0)" ::: "memory");
    __builtin_amdgcn_sched_barrier(0);
    __builtin_amdgcn_s_setprio(1);
#pragma unroll
    for (int mi = 0; mi < 4; ++mi)
#pragma unroll
      for (int ni = 0; ni < 2; ++ni)
#pragma unroll
        for (int kk = 0; kk < 2; ++kk)
          acc[mi][ni + 2] = __builtin_amdgcn_mfma_f32_16x16x32_bf16(
              __builtin_bit_cast(bf16x8, af0[mi][kk]), __builtin_bit_cast(bf16x8, bf1[ni][kk]),
              acc[mi][ni + 2], 0, 0, 0);
    __builtin_amdgcn_s_setprio(0);
    __builtin_amdgcn_s_barrier();

    if (st2) stageB(buf, 0, t + 2);
    __builtin_amdgcn_s_barrier();
    __builtin_amdgcn_s_setprio(1);
#pragma unroll
    for (int mi = 0; mi < 4; ++mi)
#pragma unroll
      for (int ni = 0; ni < 2; ++ni)
#pragma unroll
        for (int kk = 0; kk < 2; ++kk)
          acc[mi + 4][ni + 2] = __builtin_amdgcn_mfma_f32_16x16x32_bf16(
              __builtin_bit_cast(bf16x8, af1[mi][kk]), __builtin_bit_cast(bf16x8, bf1[ni][kk]),
              acc[mi + 4][ni + 2], 0, 0, 0);
    __builtin_amdgcn_s_setprio(0);
    __builtin_amdgcn_s_barrier();

    if (st2) stageA(buf, 1, t + 2);
    __builtin_amdgcn_s_barrier();
    __builtin_amdgcn_s_setprio(1);
#pragma unroll
    for (int mi = 0; mi < 4; ++mi)
#pragma unroll
      for (int ni = 0; ni < 2; ++ni)
#pragma unroll
        for (int kk = 0; kk < 2; ++kk)
          acc[mi + 4][ni] = __builtin_amdgcn_mfma_f32_16x16x32_bf16(
              __builtin_bit_cast(bf16x8, af1[mi][kk]), __builtin_bit_cast(bf16x8, bf0[ni][kk]),
              acc[mi + 4][ni], 0, 0, 0);
    __builtin_amdgcn_s_setprio(0);
    if (st2)       asm volatile("s_waitcnt vmcnt(6)" ::: "memory");
    else if (st1)  asm volatile("s_waitcnt vmcnt(0)" ::: "memory");
    __builtin_amdgcn_s_barrier();
  }

#pragma unroll
  for (int ni = 0; ni < 4; ++ni) {
    const int gn = n0 + wc * 64 + ni * 16 + fr;
    const float bv = bias[gn];
#pragma unroll
    for (int mi = 0; mi < 8; ++mi) {
      const int gm = m0 + wr * 128 + mi * 16 + kg * 4;
#pragma unroll
      for (int j = 0; j < 4; ++j)
        C[(size_t)(gm + j) * N + gn] = acc[mi][ni][j] + bv;
    }
  }
}

// ===================== UA/UV batched small GEMM (round-2, unchanged) =======
__global__ __launch_bounds__(256)
void uav_gemm(const unsigned short* __restrict__ vAV, const unsigned short* __restrict__ w1,
              unsigned short* __restrict__ UAV) {
  __shared__ __align__(16) unsigned short lA[128 * 32];
  __shared__ __align__(16) unsigned short lB[128 * 32];

  const int zb = blockIdx.z;
  const int tensor = zb >> 3, h = zb & 7;
  const unsigned short* Ab = vAV + (size_t)tensor * (1024 * 1024) + h * 128;
  const unsigned short* Bb = w1 + h * 128;
  unsigned short* Cb = UAV + (size_t)tensor * (1024 * 8192) + h * 1024;

  const int t = threadIdx.x;
  const int m0 = blockIdx.y * 128, n0 = blockIdx.x * 128;
  const int lane = t & 63, wv = t >> 6;
  const int wrow = (wv >> 1) * 64, wcol = (wv & 1) * 64;
  const int fr = lane & 15, kg = lane >> 4;

  f32x4 acc[4][4] = {};

  const int r  = t >> 2;
  const int c8 = (t & 3) * 8;
  const unsigned short* ga = Ab + (size_t)(m0 + r) * 1024 + c8;
  const unsigned short* gb = Bb + (size_t)(n0 + r) * 1024 + c8;

  for (int k0 = 0; k0 < 128; k0 += 32) {
    __syncthreads();
    g2l16(ga + k0,             &lA[t * 8]);
    g2l16(ga + k0 + 64 * 1024, &lA[2048 + t * 8]);
    g2l16(gb + k0,             &lB[t * 8]);
    g2l16(gb + k0 + 64 * 1024, &lB[2048 + t * 8]);
    __syncthreads();

    u16x8 af[4], bg_[4];
#pragma unroll
    for (int mi = 0; mi < 4; ++mi)
      af[mi] = *reinterpret_cast<const u16x8*>(&lA[(wrow + mi * 16 + fr) * 32 + kg * 8]);
#pragma unroll
    for (int ni = 0; ni < 4; ++ni)
      bg_[ni] = *reinterpret_cast<const u16x8*>(&lB[(wcol + ni * 16 + fr) * 32 + kg * 8]);
#pragma unroll
    for (int mi = 0; mi < 4; ++mi)
#pragma unroll
      for (int ni = 0; ni < 4; ++ni)
        acc[mi][ni] = __builtin_amdgcn_mfma_f32_16x16x32_bf16(
            __builtin_bit_cast(bf16x8, af[mi]), __builtin_bit_cast(bf16x8, bg_[ni]),
            acc[mi][ni], 0, 0, 0);
  }

  const int rg = kg * 4;
#pragma unroll
  for (int ni = 0; ni < 4; ++ni) {
    const int gn = n0 + wcol + ni * 16 + fr;
#pragma unroll
    for (int mi = 0; mi < 4; ++mi) {
      const int gm = m0 + wrow + mi * 16 + rg;
#pragma unroll
      for (int j = 0; j < 4; ++j)
        Cb[(size_t)(gm + j) * 8192 + gn] = f2bf(acc[mi][ni][j]);
    }
  }
}

// ============== fused score + hid assembly (one block per (b,g)) ===========
// phase 1: pA[s][h] = sigmoid((q.kA - q.kV)/sqrt(128))  -> LDS
// phase 2: hid[b,s,g,n] = relu(b1 + sumUV + sum_h pA*(UA-UV))
__global__ __launch_bounds__(256)
void score_hid_kernel(const unsigned short* __restrict__ q,
                      const unsigned short* __restrict__ kAV,
                      const unsigned short* __restrict__ UAV,
                      const float* __restrict__ b1,
                      unsigned short* __restrict__ hid) {
  const int bg = blockIdx.x;
  const int b = bg >> 6, g = bg & 63;
  __shared__ float sk[2][D_MODEL];
  __shared__ float pAl[NSEN][N_HEAD];
  const size_t rowA = (size_t)bg * D_MODEL;
  const size_t rowV = rowA + (size_t)BS * NSEG * D_MODEL;
  for (int i = threadIdx.x; i < D_MODEL; i += 256) {
    sk[0][i] = bf2f(kAV[rowA + i]);
    sk[1][i] = bf2f(kAV[rowV + i]);
  }
  __syncthreads();

  const int h = threadIdx.x >> 5;
  const int l = threadIdx.x & 31;
  const float scale = 0.08838834764831845f;  // 1/sqrt(128)

  for (int s = 0; s < NSEN; ++s) {
    const unsigned short* pq = q + ((size_t)(b * NSEN + s)) * D_MODEL + h * DK;
    float la = 0.f, lv = 0.f;
#pragma unroll
    for (int e = 0; e < 4; ++e) {
      int d = l + e * 32;
      float qv = bf2f(pq[d]);
      la += qv * sk[0][h * DK + d];
      lv += qv * sk[1][h * DK + d];
    }
#pragma unroll
    for (int off = 16; off; off >>= 1) {
      la += __shfl_xor(la, off, 32);
      lv += __shfl_xor(lv, off, 32);
    }
    if (l == 0) pAl[s][h] = 1.f / (1.f + __expf((lv - la) * scale));
  }
  __syncthreads();

  // ---- hid assembly ----
  const int n0 = threadIdx.x * 4;
  const unsigned short* ua = UAV + (size_t)bg * 8192 + n0;
  const unsigned short* uv = ua + (size_t)1024 * 8192;

  float dU[N_HEAD][4];
  float base[4];
#pragma unroll
  for (int j = 0; j < 4; ++j) base[j] = b1[n0 + j];
#pragma unroll
  for (int hh = 0; hh < N_HEAD; ++hh) {
    ushort4 a4 = *reinterpret_cast<const ushort4*>(ua + hh * 1024);
    ushort4 v4 = *reinterpret_cast<const ushort4*>(uv + hh * 1024);
    float va[4] = {bf2f(a4.x), bf2f(a4.y), bf2f(a4.z), bf2f(a4.w)};
    float vv[4] = {bf2f(v4.x), bf2f(v4.y), bf2f(v4.z), bf2f(v4.w)};
#pragma unroll
    for (int j = 0; j < 4; ++j) { dU[hh][j] = va[j] - vv[j]; base[j] += vv[j]; }
  }

  for (int s = 0; s < NSEN; ++s) {
    float val[4] = {base[0], base[1], base[2], base[3]};
#pragma unroll
    for (int hh = 0; hh < N_HEAD; ++hh) {
      const float p = pAl[s][hh];
#pragma unroll
      for (int j = 0; j < 4; ++j) val[j] = fmaf(p, dU[hh][j], val[j]);
    }
    ushort4 o;
    o.x = f2bf(val[0] > 0.f ? val[0] : 0.f);
    o.y = f2bf(val[1] > 0.f ? val[1] : 0.f);
    o.z = f2bf(val[2] > 0.f ? val[2] : 0.f);
    o.w = f2bf(val[3] > 0.f ? val[3] : 0.f);
    size_t orow = ((size_t)(b * NSEN + s) * NSEG + g) * D_MODEL + n0;
    *reinterpret_cast<ushort4*>(hid + orow) = o;
  }
}

extern "C" void kernel_launch(void* const* d_in, const int* in_sizes, int n_in,
                              void* d_out, int out_size, void* d_ws, size_t ws_size,
                              hipStream_t stream) {
  const float* A  = (const float*)d_in[0];
  const float* V  = (const float*)d_in[1];
  const float* S  = (const float*)d_in[2];
  const float* wA = (const float*)d_in[3];  const float* bA = (const float*)d_in[4];
  const float* wV = (const float*)d_in[5];  const float* bV = (const float*)d_in[6];
  const float* wS = (const float*)d_in[7];  const float* bS = (const float*)d_in[8];
  const float* wq = (const float*)d_in[9];  const float* bq = (const float*)d_in[10];
  const float* wk = (const float*)d_in[11]; const float* bk = (const float*)d_in[12];
  const float* wv = (const float*)d_in[13]; const float* bv = (const float*)d_in[14];
  const float* w1 = (const float*)d_in[15]; const float* b1 = (const float*)d_in[16];
  const float* w2 = (const float*)d_in[17]; const float* b2 = (const float*)d_in[18];

  const int nAV = BS * NSEG * D_MODEL;         // 1,048,576
  const int nS  = BS * NSEN * D_MODEL;         // 524,288
  const int nW  = D_MODEL * D_MODEL;           // 1,048,576
  const int nCT = BS * NSEN * NSEG * D_MODEL;  // 33,554,432
  const int nU  = 2 * 1024 * 8 * 1024;         // 16,777,216

  char* ws = (char*)d_ws;
  size_t off = 0;
  auto carve = [&](size_t elems) {
    unsigned short* p = (unsigned short*)(ws + off);
    off += elems * sizeof(unsigned short);
    return p;
  };
  unsigned short* bwA = carve(nW);
  unsigned short* bwV = carve(nW);
  unsigned short* bwS = carve(nW);
  unsigned short* bwq = carve(nW);
  unsigned short* bwk = carve(nW);
  unsigned short* bwv = carve(nW);
  unsigned short* bw1 = carve(nW);
  unsigned short* bw2 = carve(nW);
  unsigned short* xA  = carve(nAV);
  unsigned short* xV  = carve(nAV);
  unsigned short* xS  = carve(nS);
  unsigned short* A1V1 = carve(2 * nAV);   // A1 rows then V1 rows
  unsigned short* S1  = carve(nS);
  unsigned short* qb  = carve(nS);
  unsigned short* kAV = carve(2 * nAV);    // kA rows then kV rows
  unsigned short* vAV = carve(2 * nAV);    // vA rows then vV rows
  unsigned short* UAV = carve(nU);         // [2][1024][8][1024]
  unsigned short* hid = carve(nCT);        // 64MB
  (void)ws_size; (void)n_in; (void)in_sizes; (void)out_size;

  // 1) all fp32->bf16 converts in one launch
  CvtB cv;
  cv.s[0] = wA; cv.d[0] = bwA; cv.n4[0] = nW / 4;
  cv.s[1] = wV; cv.d[1] = bwV; cv.n4[1] = nW / 4;
  cv.s[2] = wS; cv.d[2] = bwS; cv.n4[2] = nW / 4;
  cv.s[3] = wq; cv.d[3] = bwq; cv.n4[3] = nW / 4;
  cv.s[4] = wk; cv.d[4] = bwk; cv.n4[4] = nW / 4;
  cv.s[5] = wv; cv.d[5] = bwv; cv.n4[5] = nW / 4;
  cv.s[6] = w1; cv.d[6] = bw1; cv.n4[6] = nW / 4;
  cv.s[7] = w2; cv.d[7] = bw2; cv.n4[7] = nW / 4;
  cv.s[8] = A;  cv.d[8] = xA;  cv.n4[8] = nAV / 4;
  cv.s[9] = V;  cv.d[9] = xV;  cv.n4[9] = nAV / 4;
  cv.s[10] = S; cv.d[10] = xS; cv.n4[10] = nS / 4;
  cvtall_kernel<<<dim3(1024, 11), dim3(256), 0, stream>>>(cv);

  // 2) input projections A,V,S in one batched launch (tiles: 128,128,64)
  GBatch pj;
  pj.s[0] = {xA, bwA, bA, A1V1};        pj.end[0] = 128;
  pj.s[1] = {xV, bwV, bV, A1V1 + nAV};  pj.end[1] = 256;
  pj.s[2] = {xS, bwS, bS, S1};          pj.end[2] = 320;
  gemm64_bt<<<dim3(320), 256, 0, stream>>>(pj);

  // 3) q,k,v projections in one batched launch (tiles: 64,256,256)
  GBatch qkv;
  qkv.s[0] = {S1,   bwq, bq, qb};   qkv.end[0] = 64;
  qkv.s[1] = {A1V1, bwk, bk, kAV};  qkv.end[1] = 320;
  qkv.s[2] = {A1V1, bwv, bv, vAV};  qkv.end[2] = 576;
  gemm64_bt<<<dim3(576), 256, 0, stream>>>(qkv);

  // 4) UA/UV batched small GEMMs
  uav_gemm<<<dim3(8, 8, 16), dim3(256), 0, stream>>>(vAV, bw1, UAV);

  // 5) fused scores + hid assembly
  score_hid_kernel<<<dim3(BS * NSEG), dim3(256), 0, stream>>>(qb, kAV, UAV, b1, hid);

  // 6) FF2 on the 8-phase 256^2 schedule
  gemm8p_bt<<<dim3(512), 512, 0, stream>>>(hid, bw2, b2, (float*)d_out,
                                           32768, 1024, 1024, 4);
}